// Round 10
// baseline (278.753 us; speedup 1.0000x reference)
//
#include <hip/hip_runtime.h>
#include <stdint.h>

#define NN 10000
#define NE 100000

__device__ __forceinline__ float bu2f(uint16_t u) {
    return __uint_as_float(((uint32_t)u) << 16);
}
__device__ __forceinline__ float blo(uint32_t v) { return __uint_as_float(v << 16); }
__device__ __forceinline__ float bhi(uint32_t v) { return __uint_as_float(v & 0xffff0000u); }
__device__ __forceinline__ uint16_t f2bu(float f) {  // RNE
    uint32_t u = __float_as_uint(f);
    return (uint16_t)((u + 0x7fffu + ((u >> 16) & 1u)) >> 16);
}
// RULE (empirical, R1-R12): float d_in tensors are read ONLY via runtime-dual-path
// accessors (never hard-coded single-dtype).
__device__ __forceinline__ float ldf(const void* p, size_t i, int f32) {
    return f32 ? ((const float*)p)[i] : bu2f(((const uint16_t*)p)[i]);
}
struct f8 { float v[8]; };
__device__ __forceinline__ f8 ldf8(const void* p, size_t i, int f32) {
    f8 r;
    if (f32) {
        const float4* q = (const float4*)((const float*)p + i);
        float4 a = q[0], b = q[1];
        r.v[0]=a.x; r.v[1]=a.y; r.v[2]=a.z; r.v[3]=a.w;
        r.v[4]=b.x; r.v[5]=b.y; r.v[6]=b.z; r.v[7]=b.w;
    } else {
        uint4 u = *(const uint4*)((const uint16_t*)p + i);
        r.v[0]=blo(u.x); r.v[1]=bhi(u.x); r.v[2]=blo(u.y); r.v[3]=bhi(u.y);
        r.v[4]=blo(u.z); r.v[5]=bhi(u.z); r.v[6]=blo(u.w); r.v[7]=bhi(u.w);
    }
    return r;
}
__device__ __forceinline__ void stf(void* p, size_t i, float v, int f32) {
    if (f32) ((float*)p)[i] = v;
    else ((uint16_t*)p)[i] = f2bu(v);
}
__device__ __forceinline__ int clampi(int v, int lo, int hi) {
    return min(max(v, lo), hi);
}

// ---------- K1: zero (agg|deg|ABC|dv) + PARALLEL dtype detect ----------
__global__ __launch_bounds__(256) void k_init(
    const void* __restrict__ x, float4* __restrict__ zbase, int* __restrict__ flag)
{
    __shared__ int red[256];
    int bid = blockIdx.x;
    int tid = threadIdx.x;
    if (bid < 657) {
        int idx = bid * 256 + tid;
        if (idx < 168088) zbase[idx] = make_float4(0.f, 0.f, 0.f, 0.f);
    } else {
        const uint16_t* p = (const uint16_t*)x;
        int c = 0;
        #pragma unroll
        for (int q = 0; q < 4; q++) {
            float a = fabsf(bu2f(p[tid + q * 256]));
            if (a > 1e-3f && a < 16.0f) c++;
        }
        red[tid] = c;
        __syncthreads();
        #pragma unroll
        for (int d = 128; d > 0; d >>= 1) {
            if (tid < d) red[tid] += red[tid + d];
            __syncthreads();
        }
        if (tid == 0) *flag = (red[0] < 870) ? 1 : 0;  // 1 = fp32 inputs
    }
}

// ---------- K2: MLP | abc | count+rank | stage ----------
// [0,3125): edge MLP 32/block   [3125,3637): abc partials
// [3637,4028): count + rank     [4028,4185): stage x    [4185]: stage root
__global__ __launch_bounds__(256, 4) void k_prepRest(
    const void* __restrict__ x, const void* __restrict__ root,
    const void* __restrict__ tw1, const void* __restrict__ tw2,
    const void* __restrict__ tw3,
    const void* __restrict__ tb1, const void* __restrict__ tb2,
    const void* __restrict__ tb3,
    const void* __restrict__ proj_w,
    const void* __restrict__ edge_attr, const void* __restrict__ w1,
    const void* __restrict__ b1,
    const int* __restrict__ ei, const int* __restrict__ flag,
    float* __restrict__ xs_f, float* __restrict__ root_f,
    float* __restrict__ A, float* __restrict__ B, float* __restrict__ C,
    float* __restrict__ dv,
    int* __restrict__ outdeg, int* __restrict__ indeg, int* __restrict__ rank,
    uint16_t* __restrict__ h_edge)
{
    int bid = blockIdx.x;
    int tid = threadIdx.x;
    __shared__ float w1s[512];
    __shared__ float b1s[32];
    __shared__ float eas[32][16];

    if (bid < 3125) {                        // ---- edge MLP, 32 edges/block ----
        int f32 = *flag;
        int e0 = bid * 32;
        if (tid < 64) {
            f8 r = ldf8(w1, (size_t)tid * 8, f32);
            #pragma unroll
            for (int q = 0; q < 8; q++) w1s[tid * 8 + q] = r.v[q];
        } else if (tid < 128) {
            int t = tid - 64;
            f8 r = ldf8(edge_attr, (size_t)e0 * 16 + (size_t)t * 8, f32);
            int el = t >> 1, half = (t & 1) * 8;
            #pragma unroll
            for (int q = 0; q < 8; q++) eas[el][half + q] = r.v[q];
        } else if (tid < 160) {
            b1s[tid - 128] = ldf(b1, tid - 128, f32);
        }
        __syncthreads();
        int el = tid >> 5, jj = tid & 31;
        float wreg[16];
        #pragma unroll
        for (int k = 0; k < 16; k++) wreg[k] = w1s[k * 32 + jj];
        float bj = b1s[jj];
        #pragma unroll
        for (int r = 0; r < 4; r++) {
            int e = el + r * 8;
            float acc = bj;
            #pragma unroll
            for (int k = 0; k < 16; k++) acc = fmaf(eas[e][k], wreg[k], acc);
            h_edge[(size_t)(e0 + e) * 32 + jj] = f2bu(fmaxf(acc, 0.0f));
        }
    } else if (bid < 3637) {                 // ---- abc partials, 512 blocks ----
        int f32 = *flag;
        int beta = bid - 3125;               // [0,512)
        int i = beta >> 3;                   // [0,64)
        int chunk = beta & 7;                // [0,8)
        int o = tid & 63, sub = tid >> 6;
        int cc0 = chunk * 8 + sub * 2;
        float a = 0.f, b = 0.f, c = 0.f, d = 0.f;
        #pragma unroll
        for (int m = 0; m < 2; m++) {
            int cc = cc0 + m;
            float p0 = ldf(proj_w, (size_t)cc * 64 + o, f32);
            float p1 = ldf(proj_w, (size_t)(64 + cc) * 64 + o, f32);
            float p2 = ldf(proj_w, (size_t)(128 + cc) * 64 + o, f32);
            size_t base = (size_t)cc * 192 + i * 3;
            a = fmaf(ldf(tw1, base + 1, f32), p0, a);
            a = fmaf(ldf(tw2, base + 1, f32), p1, a);
            a = fmaf(ldf(tw3, base + 1, f32), p2, a);
            b = fmaf(ldf(tw2, base + 0, f32), p1, b);
            c = fmaf(ldf(tw1, base + 0, f32), p0, c);
            if (i == 0) {
                d = fmaf(ldf(tb1, cc, f32), p0, d);
                d = fmaf(ldf(tb2, cc, f32), p1, d);
                d = fmaf(ldf(tb3, cc, f32), p2, d);
            }
        }
        unsafeAtomicAdd(&A[i * 64 + o], a);
        unsafeAtomicAdd(&B[i * 64 + o], b);
        unsafeAtomicAdd(&C[i * 64 + o], c);
        if (i == 0) unsafeAtomicAdd(&dv[o], d);
    } else if (bid < 4028) {                 // ---- count + rank ----
        int e = (bid - 3637) * 256 + tid;
        if (e < NE) {
            int src = clampi(ei[e], 0, NN - 1);
            rank[e] = atomicAdd(&outdeg[src], 1);
            atomicAdd(&indeg[clampi(ei[NE + e], 0, NN - 1)], 1);
        }
    } else if (bid < 4185) {                 // ---- stage x ----
        int f32 = *flag;
        int v8 = (bid - 4028) * 256 + tid;
        if (v8 < 40000) {
            f8 r = ldf8(x, (size_t)v8 * 8, f32);
            float4* o = (float4*)(xs_f + (size_t)v8 * 8);
            o[0] = make_float4(r.v[0], r.v[1], r.v[2], r.v[3]);
            o[1] = make_float4(r.v[4], r.v[5], r.v[6], r.v[7]);
        }
    } else {                                 // ---- stage root ----
        int f32 = *flag;
        f8 r = ldf8(root, (size_t)tid * 8, f32);
        float4* o = (float4*)(root_f + (size_t)tid * 8);
        o[0] = make_float4(r.v[0], r.v[1], r.v[2], r.v[3]);
        o[1] = make_float4(r.v[4], r.v[5], r.v[6], r.v[7]);
    }
}

// ---------- K3: exclusive scan outdeg -> offs (1 block, brief) ----------
__global__ __launch_bounds__(1024) void k_scan(
    const int* __restrict__ outdeg, int* __restrict__ offs)
{
    __shared__ int sums[1024];
    const int CH = 10;
    int tid = threadIdx.x;
    int base = tid * CH;
    int v[CH];
    int s = 0;
    #pragma unroll
    for (int k = 0; k < CH; k++) {
        int i = base + k;
        int c = (i < NN) ? outdeg[i] : 0;
        v[k] = s;
        s += c;
    }
    sums[tid] = s;
    __syncthreads();
    for (int d = 1; d < 1024; d <<= 1) {
        int t = (tid >= d) ? sums[tid - d] : 0;
        __syncthreads();
        if (tid >= d) sums[tid] += t;
        __syncthreads();
    }
    int prefix = (tid == 0) ? 0 : sums[tid - 1];
    #pragma unroll
    for (int k = 0; k < CH; k++) {
        int i = base + k;
        if (i < NN) offs[i] = prefix + v[k];
    }
}

// ---------- K4: scatter, 1 edge/thread (atomic-free via rank) ----------
// Writes sorted_dst + h row into sorted order (sorted_src no longer needed:
// k_Tmsg knows the src implicitly from the CSR range it owns).
__global__ __launch_bounds__(256) void k_scat(
    const int* __restrict__ ei, const int* __restrict__ offs,
    const int* __restrict__ rank,
    int* __restrict__ sorted_dst, int* __restrict__ sorted_eid,
    const uint16_t* __restrict__ h_edge, uint16_t* __restrict__ h_srt, int hs_mode)
{
    int e = blockIdx.x * 256 + threadIdx.x;
    if (e < NE) {
        int src = clampi(ei[e], 0, NN - 1);
        int dst = clampi(ei[NE + e], 0, NN - 1);
        int pos = clampi(offs[src] + rank[e], 0, NE - 1);
        sorted_dst[pos] = dst;
        if (hs_mode) {
            const uint4* hs = (const uint4*)(h_edge + (size_t)e * 32);
            uint4* hd = (uint4*)(h_srt + (size_t)pos * 32);
            hd[0] = hs[0]; hd[1] = hs[1]; hd[2] = hs[2]; hd[3] = hs[3];
        } else {
            sorted_eid[pos] = e;
        }
    }
}

// ---------- K5: FUSED compute_T + messages (T never touches global) ----------
// 1250 blocks x 8 nodes. GEMM identical to old k_prepT; per node s the acc
// tile goes through the 4KB LDS transpose and is consumed IN-REGISTER by the
// 4 waves, which stride over that node's CSR edge range and accumulate agg.
// Eliminates: T (40MB wr + ~80MB gather rd), xb (5MB), sorted_src, msg kernel.
__global__ __launch_bounds__(256) void k_Tmsg(
    const void* __restrict__ x,
    const void* __restrict__ w2, const void* __restrict__ b2,
    const int* __restrict__ flag,
    const int* __restrict__ offs, const int* __restrict__ outdeg,
    const int* __restrict__ sorted_dst, const uint16_t* __restrict__ h_srt,
    const int* __restrict__ sorted_eid, const uint16_t* __restrict__ h_edge,
    int hs_mode, float* __restrict__ agg)
{
    int bid = blockIdx.x;
    int tid = threadIdx.x;
    __shared__ float xs[8][32];
    __shared__ uint16_t Ts[32][64];

    int f32 = *flag;
    int n0 = bid * 8;
    if (tid < 32) {
        f8 r = ldf8(x, (size_t)n0 * 32 + (size_t)tid * 8, f32);
        int base = tid * 8;
        #pragma unroll
        for (int q = 0; q < 8; q++) xs[(base + q) >> 5][(base + q) & 31] = r.v[q];
    }
    __syncthreads();
    int j = tid >> 3;                    // hk in [0,32)
    int o0 = (tid & 7) * 8;              // o base in [0,64)
    float acc[8][8];
    #pragma unroll
    for (int s = 0; s < 8; s++)
        #pragma unroll
        for (int r = 0; r < 8; r++) acc[s][r] = 0.0f;
    if (f32) {
        const float* wb = (const float*)w2 + (size_t)j * 2048 + o0;
        for (int i = 0; i < 32; i++) {
            float4 a4 = *(const float4*)(wb + i * 64);
            float4 b4 = *(const float4*)(wb + i * 64 + 4);
            #pragma unroll
            for (int s = 0; s < 8; s++) {
                float xv = xs[s][i];
                acc[s][0] = fmaf(xv, a4.x, acc[s][0]); acc[s][1] = fmaf(xv, a4.y, acc[s][1]);
                acc[s][2] = fmaf(xv, a4.z, acc[s][2]); acc[s][3] = fmaf(xv, a4.w, acc[s][3]);
                acc[s][4] = fmaf(xv, b4.x, acc[s][4]); acc[s][5] = fmaf(xv, b4.y, acc[s][5]);
                acc[s][6] = fmaf(xv, b4.z, acc[s][6]); acc[s][7] = fmaf(xv, b4.w, acc[s][7]);
            }
        }
    } else {
        const uint16_t* wb = (const uint16_t*)w2 + (size_t)j * 2048 + o0;
        for (int i = 0; i < 32; i++) {
            uint4 u = *(const uint4*)(wb + i * 64);
            float w0 = blo(u.x), w1_ = bhi(u.x), w2_ = blo(u.y), w3 = bhi(u.y);
            float w4 = blo(u.z), w5 = bhi(u.z), w6 = blo(u.w), w7 = bhi(u.w);
            #pragma unroll
            for (int s = 0; s < 8; s++) {
                float xv = xs[s][i];
                acc[s][0] = fmaf(xv, w0, acc[s][0]); acc[s][1] = fmaf(xv, w1_, acc[s][1]);
                acc[s][2] = fmaf(xv, w2_, acc[s][2]); acc[s][3] = fmaf(xv, w3, acc[s][3]);
                acc[s][4] = fmaf(xv, w4, acc[s][4]); acc[s][5] = fmaf(xv, w5, acc[s][5]);
                acc[s][6] = fmaf(xv, w6, acc[s][6]); acc[s][7] = fmaf(xv, w7, acc[s][7]);
            }
        }
    }

    int o = tid & 63;                    // lane = output channel
    int w = tid >> 6;                    // wave id
    for (int s = 0; s < 8; s++) {
        __syncthreads();                 // prior phase's Ts reads complete
        uint4 ov;
        ov.x = ((uint32_t)f2bu(acc[s][1]) << 16) | f2bu(acc[s][0]);
        ov.y = ((uint32_t)f2bu(acc[s][3]) << 16) | f2bu(acc[s][2]);
        ov.z = ((uint32_t)f2bu(acc[s][5]) << 16) | f2bu(acc[s][4]);
        ov.w = ((uint32_t)f2bu(acc[s][7]) << 16) | f2bu(acc[s][6]);
        *(uint4*)&Ts[j][o0] = ov;        // contiguous 1KB/wave
        __syncthreads();
        // lane o reads its T column: Ts[k][o], 2 lanes/bank -> free (m136)
        float tv[32];
        #pragma unroll
        for (int k = 0; k < 32; k++) tv[k] = bu2f(Ts[k][o]);
        // xb[s][o] = x[s] . b2[:,o] (fp32, same value the old xb buffer held)
        float xbv = 0.0f;
        if (f32) {
            const float* b2f = (const float*)b2;
            #pragma unroll
            for (int i = 0; i < 32; i++) xbv = fmaf(xs[s][i], b2f[i * 64 + o], xbv);
        } else {
            const uint16_t* b2u = (const uint16_t*)b2;
            #pragma unroll
            for (int i = 0; i < 32; i++) xbv = fmaf(xs[s][i], bu2f(b2u[i * 64 + o]), xbv);
        }
        int node = n0 + s;
        int beg = offs[node];
        int end = beg + outdeg[node];
        for (int idx = beg + w; idx < end; idx += 4) {
            int pos = clampi(idx, 0, NE - 1);
            const uint4* hp;
            if (hs_mode) hp = (const uint4*)(h_srt + (size_t)pos * 32);
            else hp = (const uint4*)(h_edge + (size_t)clampi(sorted_eid[pos], 0, NE - 1) * 32);
            uint4 a = hp[0], b = hp[1], c = hp[2], d = hp[3];
            int dst = clampi(sorted_dst[pos], 0, NN - 1);
            float s0 = 0.f, s1 = 0.f, s2 = 0.f, s3 = 0.f;
            s0 = fmaf(blo(a.x), tv[0],  s0); s0 = fmaf(bhi(a.x), tv[1],  s0);
            s0 = fmaf(blo(a.y), tv[2],  s0); s0 = fmaf(bhi(a.y), tv[3],  s0);
            s0 = fmaf(blo(a.z), tv[4],  s0); s0 = fmaf(bhi(a.z), tv[5],  s0);
            s0 = fmaf(blo(a.w), tv[6],  s0); s0 = fmaf(bhi(a.w), tv[7],  s0);
            s1 = fmaf(blo(b.x), tv[8],  s1); s1 = fmaf(bhi(b.x), tv[9],  s1);
            s1 = fmaf(blo(b.y), tv[10], s1); s1 = fmaf(bhi(b.y), tv[11], s1);
            s1 = fmaf(blo(b.z), tv[12], s1); s1 = fmaf(bhi(b.z), tv[13], s1);
            s1 = fmaf(blo(b.w), tv[14], s1); s1 = fmaf(bhi(b.w), tv[15], s1);
            s2 = fmaf(blo(c.x), tv[16], s2); s2 = fmaf(bhi(c.x), tv[17], s2);
            s2 = fmaf(blo(c.y), tv[18], s2); s2 = fmaf(bhi(c.y), tv[19], s2);
            s2 = fmaf(blo(c.z), tv[20], s2); s2 = fmaf(bhi(c.z), tv[21], s2);
            s2 = fmaf(blo(c.w), tv[22], s2); s2 = fmaf(bhi(c.w), tv[23], s2);
            s3 = fmaf(blo(d.x), tv[24], s3); s3 = fmaf(bhi(d.x), tv[25], s3);
            s3 = fmaf(blo(d.y), tv[26], s3); s3 = fmaf(bhi(d.y), tv[27], s3);
            s3 = fmaf(blo(d.z), tv[28], s3); s3 = fmaf(bhi(d.z), tv[29], s3);
            s3 = fmaf(blo(d.w), tv[30], s3); s3 = fmaf(bhi(d.w), tv[31], s3);
            float accv = xbv + (s0 + s1) + (s2 + s3);
            unsafeAtomicAdd(&agg[(size_t)dst * 64 + o], accv);
        }
    }
}

// ---------- K6: per-node finalize; 3 independent FMA chains ----------
__global__ __launch_bounds__(256) void k_node_out(
    const float* __restrict__ agg, const int* __restrict__ indeg,
    const float* __restrict__ xs_f, const float* __restrict__ root_f,
    const void* __restrict__ bias, const void* __restrict__ h_prev,
    const float* __restrict__ A, const float* __restrict__ B,
    const float* __restrict__ C, const float* __restrict__ dv,
    const void* __restrict__ proj_b,
    const int* __restrict__ flag, void* __restrict__ out)
{
    int f32 = *flag;
    int tid = threadIdx.x;
    int s = tid >> 6, o = tid & 63;
    int n = blockIdx.x * 4 + s;
    const size_t O1 = (size_t)NN * 64;
    __shared__ float hg_s[4][64], hp1_s[4][64], hp2_s[4][64];

    float xr = 0.0f;
    const float* xp = xs_f + (size_t)n * 32;
    #pragma unroll
    for (int i = 0; i < 32; i++)
        xr = fmaf(xp[i], root_f[i * 64 + o], xr);
    float c = (float)indeg[n];
    float m = agg[(size_t)n * 64 + o] / fmaxf(c, 1.0f);
    float hg = fmaxf(m + xr + ldf(bias, o, f32), 0.0f);
    float hp1 = ldf(h_prev, (size_t)n * 192 + 64 + o, f32);
    float hp2 = ldf(h_prev, (size_t)n * 192 + 128 + o, f32);
    hg_s[s][o] = hg; hp1_s[s][o] = hp1; hp2_s[s][o] = hp2;
    stf(out, O1 + (size_t)n * 192 + o, hp1, f32);
    stf(out, O1 + (size_t)n * 192 + 64 + o, hp2, f32);
    stf(out, O1 + (size_t)n * 192 + 128 + o, hg, f32);
    __syncthreads();

    float accA = 0.f, accB = 0.f, accC = 0.f;
    #pragma unroll 8
    for (int i = 0; i < 64; i++) {
        accA = fmaf(hg_s[s][i],  A[i * 64 + o], accA);
        accB = fmaf(hp1_s[s][i], B[i * 64 + o], accB);
        accC = fmaf(hp2_s[s][i], C[i * 64 + o], accC);
    }
    float acc = dv[o] + ldf(proj_b, o, f32) + (accA + accB) + accC;
    stf(out, (size_t)n * 64 + o, acc, f32);
}

static inline size_t align64(size_t v) { return (v + 63) & ~(size_t)63; }

extern "C" void kernel_launch(void* const* d_in, const int* in_sizes, int n_in,
                              void* d_out, int out_size, void* d_ws, size_t ws_size,
                              hipStream_t stream) {
    const void* x         = d_in[0];
    const void* edge_attr = d_in[1];
    const void* h_prev    = d_in[2];
    const int*  ei        = (const int*)d_in[3];
    const void* w1     = d_in[4];
    const void* b1     = d_in[5];
    const void* w2     = d_in[6];
    const void* b2     = d_in[7];
    const void* root   = d_in[8];
    const void* bias   = d_in[9];
    const void* tw1    = d_in[10];
    const void* tb1    = d_in[11];
    const void* tw2    = d_in[12];
    const void* tb2    = d_in[13];
    const void* tw3    = d_in[14];
    const void* tb3    = d_in[15];
    const void* proj_w = d_in[16];
    const void* proj_b = d_in[17];

    char* ws = (char*)d_ws;
    size_t off = 0;
    uint16_t* h_edge = (uint16_t*)(ws + off); off = align64(off + (size_t)NE * 32 * 2);
    float* xs_f   = (float*)(ws + off); off = align64(off + (size_t)NN * 32 * 4);
    float* root_f = (float*)(ws + off); off = align64(off + (size_t)2048 * 4);
    size_t zero_base = off;  // agg|indeg|outdeg|A|B|C|dv = 2,689,408 B (168088 float4)
    float* agg    = (float*)(ws + off); off = align64(off + (size_t)NN * 64 * 4);
    int* indeg    = (int*)(ws + off);   off = align64(off + (size_t)NN * 4);
    int* outdeg   = (int*)(ws + off);   off = align64(off + (size_t)NN * 4);
    float* Amat   = (float*)(ws + off); off = align64(off + (size_t)4096 * 4);
    float* Bmat   = (float*)(ws + off); off = align64(off + (size_t)4096 * 4);
    float* Cmat   = (float*)(ws + off); off = align64(off + (size_t)4096 * 4);
    float* dvec   = (float*)(ws + off); off = align64(off + (size_t)64 * 4);
    int* offs        = (int*)(ws + off); off = align64(off + (size_t)(NN + 64) * 4);
    int* rank        = (int*)(ws + off); off = align64(off + (size_t)NE * 4);
    int* sorted_dst  = (int*)(ws + off); off = align64(off + (size_t)NE * 4);
    int* sorted_eid  = (int*)(ws + off); off = align64(off + (size_t)NE * 4);
    int* flag        = (int*)(ws + off); off = align64(off + 64);
    uint16_t* h_srt  = (uint16_t*)(ws + off);
    size_t off_end = off + (size_t)NE * 32 * 2;
    int hs_mode = (off_end <= ws_size) ? 1 : 0;  // host-side, deterministic

    k_init<<<658, 256, 0, stream>>>(x, (float4*)((char*)d_ws + zero_base), flag);
    k_prepRest<<<4186, 256, 0, stream>>>(x, root, tw1, tw2, tw3, tb1, tb2, tb3,
                                         proj_w, edge_attr, w1, b1, ei, flag,
                                         xs_f, root_f, Amat, Bmat, Cmat, dvec,
                                         outdeg, indeg, rank, h_edge);
    k_scan<<<1, 1024, 0, stream>>>(outdeg, offs);
    k_scat<<<(NE + 255) / 256, 256, 0, stream>>>(ei, offs, rank,
                                                 sorted_dst, sorted_eid,
                                                 h_edge, h_srt, hs_mode);
    k_Tmsg<<<(NN + 7) / 8, 256, 0, stream>>>(x, w2, b2, flag, offs, outdeg,
                                             sorted_dst, h_srt, sorted_eid,
                                             h_edge, hs_mode, agg);
    k_node_out<<<NN / 4, 256, 0, stream>>>(agg, indeg, xs_f, root_f, bias, h_prev,
                                           Amat, Bmat, Cmat, dvec, proj_b, flag, d_out);
}

// Round 11
// 204.226 us; speedup vs baseline: 1.3649x; 1.3649x over previous
//
#include <hip/hip_runtime.h>
#include <stdint.h>

#define NN 10000
#define NE 100000
#define CHUNK 10

__device__ __forceinline__ float bu2f(uint16_t u) {
    return __uint_as_float(((uint32_t)u) << 16);
}
__device__ __forceinline__ float blo(uint32_t v) { return __uint_as_float(v << 16); }
__device__ __forceinline__ float bhi(uint32_t v) { return __uint_as_float(v & 0xffff0000u); }
__device__ __forceinline__ uint16_t f2bu(float f) {  // RNE
    uint32_t u = __float_as_uint(f);
    return (uint16_t)((u + 0x7fffu + ((u >> 16) & 1u)) >> 16);
}
// RULE (empirical, R1-R12): float d_in tensors are read ONLY via runtime-dual-path
// accessors (never hard-coded single-dtype).
__device__ __forceinline__ float ldf(const void* p, size_t i, int f32) {
    return f32 ? ((const float*)p)[i] : bu2f(((const uint16_t*)p)[i]);
}
struct f8 { float v[8]; };
__device__ __forceinline__ f8 ldf8(const void* p, size_t i, int f32) {
    f8 r;
    if (f32) {
        const float4* q = (const float4*)((const float*)p + i);
        float4 a = q[0], b = q[1];
        r.v[0]=a.x; r.v[1]=a.y; r.v[2]=a.z; r.v[3]=a.w;
        r.v[4]=b.x; r.v[5]=b.y; r.v[6]=b.z; r.v[7]=b.w;
    } else {
        uint4 u = *(const uint4*)((const uint16_t*)p + i);
        r.v[0]=blo(u.x); r.v[1]=bhi(u.x); r.v[2]=blo(u.y); r.v[3]=bhi(u.y);
        r.v[4]=blo(u.z); r.v[5]=bhi(u.z); r.v[6]=blo(u.w); r.v[7]=bhi(u.w);
    }
    return r;
}
__device__ __forceinline__ void stf(void* p, size_t i, float v, int f32) {
    if (f32) ((float*)p)[i] = v;
    else ((uint16_t*)p)[i] = f2bu(v);
}
__device__ __forceinline__ int clampi(int v, int lo, int hi) {
    return min(max(v, lo), hi);
}

// ---------- K1: zero (agg|deg|ABC|dv) + PARALLEL dtype detect ----------
__global__ __launch_bounds__(256) void k_init(
    const void* __restrict__ x, float4* __restrict__ zbase, int* __restrict__ flag)
{
    __shared__ int red[256];
    int bid = blockIdx.x;
    int tid = threadIdx.x;
    if (bid < 657) {
        int idx = bid * 256 + tid;
        if (idx < 168088) zbase[idx] = make_float4(0.f, 0.f, 0.f, 0.f);
    } else {
        const uint16_t* p = (const uint16_t*)x;
        int c = 0;
        #pragma unroll
        for (int q = 0; q < 4; q++) {
            float a = fabsf(bu2f(p[tid + q * 256]));
            if (a > 1e-3f && a < 16.0f) c++;
        }
        red[tid] = c;
        __syncthreads();
        #pragma unroll
        for (int d = 128; d > 0; d >>= 1) {
            if (tid < d) red[tid] += red[tid + d];
            __syncthreads();
        }
        if (tid == 0) *flag = (red[0] < 870) ? 1 : 0;  // 1 = fp32 inputs
    }
}

// ---------- K2: fused prep (R5/R8 layout, verified 49-52us) ----------
// [0,1250): compute_T (T' layout [n][o][hk], per-s 4KB LDS staging)
// [1250,4375): edge MLP 32/block   [4375,4887): abc partials
// [4887,5278): count + rank        [5278,5435): stage x    [5435]: stage root
__global__ __launch_bounds__(256, 4) void k_prep(
    const void* __restrict__ x, const void* __restrict__ root,
    const void* __restrict__ tw1, const void* __restrict__ tw2,
    const void* __restrict__ tw3,
    const void* __restrict__ tb1, const void* __restrict__ tb2,
    const void* __restrict__ tb3,
    const void* __restrict__ proj_w,
    const void* __restrict__ edge_attr, const void* __restrict__ w1,
    const void* __restrict__ b1,
    const void* __restrict__ w2, const void* __restrict__ b2,
    const int* __restrict__ ei, const int* __restrict__ flag,
    float* __restrict__ xs_f, float* __restrict__ root_f,
    float* __restrict__ A, float* __restrict__ B, float* __restrict__ C,
    float* __restrict__ dv,
    int* __restrict__ outdeg, int* __restrict__ indeg, int* __restrict__ rank,
    uint16_t* __restrict__ h_edge,
    uint16_t* __restrict__ T, float* __restrict__ xb)
{
    int bid = blockIdx.x;
    int tid = threadIdx.x;
    __shared__ union PU {
        struct { float xs[8][32]; uint16_t Ts[32][64]; } t;      // 1KB + 4KB
        struct { float w1s[512]; float b1s[32]; float eas[32][16]; } mlp;
    } su;

    if (bid < 1250) {                        // ---- compute_T, 8 nodes/block ----
        int f32 = *flag;
        int n0 = bid * 8;
        if (tid < 32) {
            f8 r = ldf8(x, (size_t)n0 * 32 + (size_t)tid * 8, f32);
            int base = tid * 8;
            #pragma unroll
            for (int q = 0; q < 8; q++) su.t.xs[(base + q) >> 5][(base + q) & 31] = r.v[q];
        }
        __syncthreads();
        int j = tid >> 3;                    // hk in [0,32)
        int o0 = (tid & 7) * 8;              // o base in [0,64)
        float acc[8][8];
        #pragma unroll
        for (int s = 0; s < 8; s++)
            #pragma unroll
            for (int r = 0; r < 8; r++) acc[s][r] = 0.0f;
        if (f32) {
            const float* wb = (const float*)w2 + (size_t)j * 2048 + o0;
            for (int i = 0; i < 32; i++) {
                float4 a4 = *(const float4*)(wb + i * 64);
                float4 b4 = *(const float4*)(wb + i * 64 + 4);
                #pragma unroll
                for (int s = 0; s < 8; s++) {
                    float xv = su.t.xs[s][i];
                    acc[s][0] = fmaf(xv, a4.x, acc[s][0]); acc[s][1] = fmaf(xv, a4.y, acc[s][1]);
                    acc[s][2] = fmaf(xv, a4.z, acc[s][2]); acc[s][3] = fmaf(xv, a4.w, acc[s][3]);
                    acc[s][4] = fmaf(xv, b4.x, acc[s][4]); acc[s][5] = fmaf(xv, b4.y, acc[s][5]);
                    acc[s][6] = fmaf(xv, b4.z, acc[s][6]); acc[s][7] = fmaf(xv, b4.w, acc[s][7]);
                }
            }
        } else {
            const uint16_t* wb = (const uint16_t*)w2 + (size_t)j * 2048 + o0;
            for (int i = 0; i < 32; i++) {
                uint4 u = *(const uint4*)(wb + i * 64);
                float w0 = blo(u.x), w1_ = bhi(u.x), w2_ = blo(u.y), w3 = bhi(u.y);
                float w4 = blo(u.z), w5 = bhi(u.z), w6 = blo(u.w), w7 = bhi(u.w);
                #pragma unroll
                for (int s = 0; s < 8; s++) {
                    float xv = su.t.xs[s][i];
                    acc[s][0] = fmaf(xv, w0, acc[s][0]); acc[s][1] = fmaf(xv, w1_, acc[s][1]);
                    acc[s][2] = fmaf(xv, w2_, acc[s][2]); acc[s][3] = fmaf(xv, w3, acc[s][3]);
                    acc[s][4] = fmaf(xv, w4, acc[s][4]); acc[s][5] = fmaf(xv, w5, acc[s][5]);
                    acc[s][6] = fmaf(xv, w6, acc[s][6]); acc[s][7] = fmaf(xv, w7, acc[s][7]);
                }
            }
        }
        // per-s transpose through a 4KB tile: write [hk][o], read [o][hk]
        int k = tid >> 6, o = tid & 63;
        #pragma unroll
        for (int s = 0; s < 8; s++) {
            uint4 ov;
            ov.x = ((uint32_t)f2bu(acc[s][1]) << 16) | f2bu(acc[s][0]);
            ov.y = ((uint32_t)f2bu(acc[s][3]) << 16) | f2bu(acc[s][2]);
            ov.z = ((uint32_t)f2bu(acc[s][5]) << 16) | f2bu(acc[s][4]);
            ov.w = ((uint32_t)f2bu(acc[s][7]) << 16) | f2bu(acc[s][6]);
            *(uint4*)&su.t.Ts[j][o0] = ov;               // contiguous 1KB/wave
            __syncthreads();
            uint16_t v0 = su.t.Ts[k * 8 + 0][o];          // 2 lanes/bank: free (m136)
            uint16_t v1 = su.t.Ts[k * 8 + 1][o];
            uint16_t v2 = su.t.Ts[k * 8 + 2][o];
            uint16_t v3 = su.t.Ts[k * 8 + 3][o];
            uint16_t v4 = su.t.Ts[k * 8 + 4][o];
            uint16_t v5 = su.t.Ts[k * 8 + 5][o];
            uint16_t v6 = su.t.Ts[k * 8 + 6][o];
            uint16_t v7 = su.t.Ts[k * 8 + 7][o];
            uint4 tv_;
            tv_.x = (uint32_t)v0 | ((uint32_t)v1 << 16);
            tv_.y = (uint32_t)v2 | ((uint32_t)v3 << 16);
            tv_.z = (uint32_t)v4 | ((uint32_t)v5 << 16);
            tv_.w = (uint32_t)v6 | ((uint32_t)v7 << 16);
            *(uint4*)(T + (size_t)(n0 + s) * 2048 + (size_t)o * 32 + k * 8) = tv_;
            __syncthreads();                              // before next s overwrite
        }
        // xb = x @ b2
        {
            int oo = tid & 63;
            if (f32) {
                const float* b2f = (const float*)b2;
                #pragma unroll
                for (int h = 0; h < 2; h++) {
                    int s = (tid >> 6) + h * 4;
                    float a2 = 0.0f;
                    #pragma unroll
                    for (int i = 0; i < 32; i++)
                        a2 = fmaf(su.t.xs[s][i], b2f[i * 64 + oo], a2);
                    xb[(size_t)(n0 + s) * 64 + oo] = a2;
                }
            } else {
                const uint16_t* b2u = (const uint16_t*)b2;
                #pragma unroll
                for (int h = 0; h < 2; h++) {
                    int s = (tid >> 6) + h * 4;
                    float a2 = 0.0f;
                    #pragma unroll
                    for (int i = 0; i < 32; i++)
                        a2 = fmaf(su.t.xs[s][i], bu2f(b2u[i * 64 + oo]), a2);
                    xb[(size_t)(n0 + s) * 64 + oo] = a2;
                }
            }
        }
    } else if (bid < 4375) {                 // ---- edge MLP, 32 edges/block ----
        int f32 = *flag;
        int e0 = (bid - 1250) * 32;
        if (tid < 64) {
            f8 r = ldf8(w1, (size_t)tid * 8, f32);
            #pragma unroll
            for (int q = 0; q < 8; q++) su.mlp.w1s[tid * 8 + q] = r.v[q];
        } else if (tid < 128) {
            int t = tid - 64;
            f8 r = ldf8(edge_attr, (size_t)e0 * 16 + (size_t)t * 8, f32);
            int el = t >> 1, half = (t & 1) * 8;
            #pragma unroll
            for (int q = 0; q < 8; q++) su.mlp.eas[el][half + q] = r.v[q];
        } else if (tid < 160) {
            su.mlp.b1s[tid - 128] = ldf(b1, tid - 128, f32);
        }
        __syncthreads();
        int el = tid >> 5, jj = tid & 31;
        float wreg[16];
        #pragma unroll
        for (int k = 0; k < 16; k++) wreg[k] = su.mlp.w1s[k * 32 + jj];
        float bj = su.mlp.b1s[jj];
        #pragma unroll
        for (int r = 0; r < 4; r++) {
            int e = el + r * 8;
            float acc = bj;
            #pragma unroll
            for (int k = 0; k < 16; k++) acc = fmaf(su.mlp.eas[e][k], wreg[k], acc);
            h_edge[(size_t)(e0 + e) * 32 + jj] = f2bu(fmaxf(acc, 0.0f));
        }
    } else if (bid < 4887) {                 // ---- abc partials, 512 blocks ----
        int f32 = *flag;
        int beta = bid - 4375;               // [0,512)
        int i = beta >> 3;                   // [0,64)
        int chunk = beta & 7;                // [0,8)
        int o = tid & 63, sub = tid >> 6;
        int cc0 = chunk * 8 + sub * 2;
        float a = 0.f, b = 0.f, c = 0.f, d = 0.f;
        #pragma unroll
        for (int m = 0; m < 2; m++) {
            int cc = cc0 + m;
            float p0 = ldf(proj_w, (size_t)cc * 64 + o, f32);
            float p1 = ldf(proj_w, (size_t)(64 + cc) * 64 + o, f32);
            float p2 = ldf(proj_w, (size_t)(128 + cc) * 64 + o, f32);
            size_t base = (size_t)cc * 192 + i * 3;
            a = fmaf(ldf(tw1, base + 1, f32), p0, a);
            a = fmaf(ldf(tw2, base + 1, f32), p1, a);
            a = fmaf(ldf(tw3, base + 1, f32), p2, a);
            b = fmaf(ldf(tw2, base + 0, f32), p1, b);
            c = fmaf(ldf(tw1, base + 0, f32), p0, c);
            if (i == 0) {
                d = fmaf(ldf(tb1, cc, f32), p0, d);
                d = fmaf(ldf(tb2, cc, f32), p1, d);
                d = fmaf(ldf(tb3, cc, f32), p2, d);
            }
        }
        unsafeAtomicAdd(&A[i * 64 + o], a);
        unsafeAtomicAdd(&B[i * 64 + o], b);
        unsafeAtomicAdd(&C[i * 64 + o], c);
        if (i == 0) unsafeAtomicAdd(&dv[o], d);
    } else if (bid < 5278) {                 // ---- count + rank ----
        int e = (bid - 4887) * 256 + tid;
        if (e < NE) {
            int src = clampi(ei[e], 0, NN - 1);
            rank[e] = atomicAdd(&outdeg[src], 1);
            atomicAdd(&indeg[clampi(ei[NE + e], 0, NN - 1)], 1);
        }
    } else if (bid < 5435) {                 // ---- stage x ----
        int f32 = *flag;
        int v8 = (bid - 5278) * 256 + tid;
        if (v8 < 40000) {
            f8 r = ldf8(x, (size_t)v8 * 8, f32);
            float4* o = (float4*)(xs_f + (size_t)v8 * 8);
            o[0] = make_float4(r.v[0], r.v[1], r.v[2], r.v[3]);
            o[1] = make_float4(r.v[4], r.v[5], r.v[6], r.v[7]);
        }
    } else {                                 // ---- stage root ----
        int f32 = *flag;
        f8 r = ldf8(root, (size_t)tid * 8, f32);
        float4* o = (float4*)(root_f + (size_t)tid * 8);
        o[0] = make_float4(r.v[0], r.v[1], r.v[2], r.v[3]);
        o[1] = make_float4(r.v[4], r.v[5], r.v[6], r.v[7]);
    }
}

// ---------- K3: exclusive scan outdeg -> offs (1 block, brief) ----------
__global__ __launch_bounds__(1024) void k_scan(
    const int* __restrict__ outdeg, int* __restrict__ offs)
{
    __shared__ int sums[1024];
    const int CH = 10;
    int tid = threadIdx.x;
    int base = tid * CH;
    int v[CH];
    int s = 0;
    #pragma unroll
    for (int k = 0; k < CH; k++) {
        int i = base + k;
        int c = (i < NN) ? outdeg[i] : 0;
        v[k] = s;
        s += c;
    }
    sums[tid] = s;
    __syncthreads();
    for (int d = 1; d < 1024; d <<= 1) {
        int t = (tid >= d) ? sums[tid - d] : 0;
        __syncthreads();
        if (tid >= d) sums[tid] += t;
        __syncthreads();
    }
    int prefix = (tid == 0) ? 0 : sums[tid - 1];
    #pragma unroll
    for (int k = 0; k < CH; k++) {
        int i = base + k;
        if (i < NN) offs[i] = prefix + v[k];
    }
}

// ---------- K4: scatter, 1 edge/thread, 391 blocks (atomic-free via rank) ----
__global__ __launch_bounds__(256) void k_scat(
    const int* __restrict__ ei, const int* __restrict__ offs,
    const int* __restrict__ rank,
    int* __restrict__ sorted_src, int* __restrict__ sorted_dst,
    int* __restrict__ sorted_eid,
    const uint16_t* __restrict__ h_edge, uint16_t* __restrict__ h_srt, int hs_mode)
{
    int e = blockIdx.x * 256 + threadIdx.x;
    if (e < NE) {
        int src = clampi(ei[e], 0, NN - 1);
        int dst = clampi(ei[NE + e], 0, NN - 1);
        int pos = clampi(offs[src] + rank[e], 0, NE - 1);
        sorted_src[pos] = src;
        sorted_dst[pos] = dst;
        if (hs_mode) {
            const uint4* hs = (const uint4*)(h_edge + (size_t)e * 32);
            uint4* hd = (uint4*)(h_srt + (size_t)pos * 32);
            hd[0] = hs[0]; hd[1] = hs[1]; hd[2] = hs[2]; hd[3] = hs[3];
        } else {
            sorted_eid[pos] = e;
        }
    }
}

// ---------- K5: grouped messages; h sequential + T'/xb early-issue ----------
__global__ __launch_bounds__(256) void k_msg_g(
    const uint16_t* __restrict__ h_edge, const uint16_t* __restrict__ h_srt,
    int hs_mode, const uint16_t* __restrict__ T,
    const float* __restrict__ xb, const int* __restrict__ sorted_src,
    const int* __restrict__ sorted_dst, const int* __restrict__ sorted_eid,
    float* __restrict__ agg)
{
    int wid = blockIdx.x * 4 + (threadIdx.x >> 6);
    int lane = threadIdx.x & 63;
    int p0 = wid * CHUNK;
    if (p0 >= NE) return;
    int p1 = min(p0 + CHUNK, NE);
    int cur = -1;
    float tv[32];
    float xbv = 0.0f;
    // pipeline state for the next edge to process
    int sN = clampi(sorted_src[p0], 0, NN - 1);
    const uint4* hq;
    if (hs_mode) hq = (const uint4*)(h_srt + (size_t)p0 * 32);
    else hq = (const uint4*)(h_edge + (size_t)clampi(sorted_eid[p0], 0, NE - 1) * 32);
    uint4 na = hq[0], nb = hq[1], nc = hq[2], nd = hq[3];
    const uint4* Tq = (const uint4*)(T + (size_t)sN * 2048 + (size_t)lane * 32);
    uint4 Tr0 = Tq[0], Tr1 = Tq[1], Tr2 = Tq[2], Tr3 = Tq[3];
    float xbN = xb[(size_t)sN * 64 + lane];
    for (int p = p0; p < p1; p++) {
        int s = sN;
        uint4 a = na, b = nb, c = nc, d = nd;
        if (s != cur) {                      // consume staged T'/xb registers
            cur = s;
            tv[0]=blo(Tr0.x); tv[1]=bhi(Tr0.x); tv[2]=blo(Tr0.y); tv[3]=bhi(Tr0.y);
            tv[4]=blo(Tr0.z); tv[5]=bhi(Tr0.z); tv[6]=blo(Tr0.w); tv[7]=bhi(Tr0.w);
            tv[8]=blo(Tr1.x); tv[9]=bhi(Tr1.x); tv[10]=blo(Tr1.y); tv[11]=bhi(Tr1.y);
            tv[12]=blo(Tr1.z); tv[13]=bhi(Tr1.z); tv[14]=blo(Tr1.w); tv[15]=bhi(Tr1.w);
            tv[16]=blo(Tr2.x); tv[17]=bhi(Tr2.x); tv[18]=blo(Tr2.y); tv[19]=bhi(Tr2.y);
            tv[20]=blo(Tr2.z); tv[21]=bhi(Tr2.z); tv[22]=blo(Tr2.w); tv[23]=bhi(Tr2.w);
            tv[24]=blo(Tr3.x); tv[25]=bhi(Tr3.x); tv[26]=blo(Tr3.y); tv[27]=bhi(Tr3.y);
            tv[28]=blo(Tr3.z); tv[29]=bhi(Tr3.z); tv[30]=blo(Tr3.w); tv[31]=bhi(Tr3.w);
            xbv = xbN;
        }
        int dst = clampi(sorted_dst[p], 0, NN - 1);
        if (p + 1 < p1) {                    // prefetch next h; early-issue next T'
            sN = clampi(sorted_src[p + 1], 0, NN - 1);
            const uint4* h2;
            if (hs_mode) h2 = (const uint4*)(h_srt + (size_t)(p + 1) * 32);
            else h2 = (const uint4*)(h_edge + (size_t)clampi(sorted_eid[p + 1], 0, NE - 1) * 32);
            na = h2[0]; nb = h2[1]; nc = h2[2]; nd = h2[3];
            if (sN != cur) {                 // sorted: src never repeats -> safe
                const uint4* T2q = (const uint4*)(T + (size_t)sN * 2048 + (size_t)lane * 32);
                Tr0 = T2q[0]; Tr1 = T2q[1]; Tr2 = T2q[2]; Tr3 = T2q[3];
                xbN = xb[(size_t)sN * 64 + lane];
            }
        }
        // 4 independent 8-deep chains
        float s0 = 0.f, s1 = 0.f, s2 = 0.f, s3 = 0.f;
        s0 = fmaf(blo(a.x), tv[0],  s0); s0 = fmaf(bhi(a.x), tv[1],  s0);
        s0 = fmaf(blo(a.y), tv[2],  s0); s0 = fmaf(bhi(a.y), tv[3],  s0);
        s0 = fmaf(blo(a.z), tv[4],  s0); s0 = fmaf(bhi(a.z), tv[5],  s0);
        s0 = fmaf(blo(a.w), tv[6],  s0); s0 = fmaf(bhi(a.w), tv[7],  s0);
        s1 = fmaf(blo(b.x), tv[8],  s1); s1 = fmaf(bhi(b.x), tv[9],  s1);
        s1 = fmaf(blo(b.y), tv[10], s1); s1 = fmaf(bhi(b.y), tv[11], s1);
        s1 = fmaf(blo(b.z), tv[12], s1); s1 = fmaf(bhi(b.z), tv[13], s1);
        s1 = fmaf(blo(b.w), tv[14], s1); s1 = fmaf(bhi(b.w), tv[15], s1);
        s2 = fmaf(blo(c.x), tv[16], s2); s2 = fmaf(bhi(c.x), tv[17], s2);
        s2 = fmaf(blo(c.y), tv[18], s2); s2 = fmaf(bhi(c.y), tv[19], s2);
        s2 = fmaf(blo(c.z), tv[20], s2); s2 = fmaf(bhi(c.z), tv[21], s2);
        s2 = fmaf(blo(c.w), tv[22], s2); s2 = fmaf(bhi(c.w), tv[23], s2);
        s3 = fmaf(blo(d.x), tv[24], s3); s3 = fmaf(bhi(d.x), tv[25], s3);
        s3 = fmaf(blo(d.y), tv[26], s3); s3 = fmaf(bhi(d.y), tv[27], s3);
        s3 = fmaf(blo(d.z), tv[28], s3); s3 = fmaf(bhi(d.z), tv[29], s3);
        s3 = fmaf(blo(d.w), tv[30], s3); s3 = fmaf(bhi(d.w), tv[31], s3);
        float acc = xbv + (s0 + s1) + (s2 + s3);
        unsafeAtomicAdd(&agg[(size_t)dst * 64 + lane], acc);
    }
}

// ---------- K6: per-node finalize; 3 independent FMA chains ----------
__global__ __launch_bounds__(256) void k_node_out(
    const float* __restrict__ agg, const int* __restrict__ indeg,
    const float* __restrict__ xs_f, const float* __restrict__ root_f,
    const void* __restrict__ bias, const void* __restrict__ h_prev,
    const float* __restrict__ A, const float* __restrict__ B,
    const float* __restrict__ C, const float* __restrict__ dv,
    const void* __restrict__ proj_b,
    const int* __restrict__ flag, void* __restrict__ out)
{
    int f32 = *flag;
    int tid = threadIdx.x;
    int s = tid >> 6, o = tid & 63;
    int n = blockIdx.x * 4 + s;
    const size_t O1 = (size_t)NN * 64;
    __shared__ float hg_s[4][64], hp1_s[4][64], hp2_s[4][64];

    float xr = 0.0f;
    const float* xp = xs_f + (size_t)n * 32;
    #pragma unroll
    for (int i = 0; i < 32; i++)
        xr = fmaf(xp[i], root_f[i * 64 + o], xr);
    float c = (float)indeg[n];
    float m = agg[(size_t)n * 64 + o] / fmaxf(c, 1.0f);
    float hg = fmaxf(m + xr + ldf(bias, o, f32), 0.0f);
    float hp1 = ldf(h_prev, (size_t)n * 192 + 64 + o, f32);
    float hp2 = ldf(h_prev, (size_t)n * 192 + 128 + o, f32);
    hg_s[s][o] = hg; hp1_s[s][o] = hp1; hp2_s[s][o] = hp2;
    stf(out, O1 + (size_t)n * 192 + o, hp1, f32);
    stf(out, O1 + (size_t)n * 192 + 64 + o, hp2, f32);
    stf(out, O1 + (size_t)n * 192 + 128 + o, hg, f32);
    __syncthreads();

    float accA = 0.f, accB = 0.f, accC = 0.f;
    #pragma unroll 8
    for (int i = 0; i < 64; i++) {
        accA = fmaf(hg_s[s][i],  A[i * 64 + o], accA);
        accB = fmaf(hp1_s[s][i], B[i * 64 + o], accB);
        accC = fmaf(hp2_s[s][i], C[i * 64 + o], accC);
    }
    float acc = dv[o] + ldf(proj_b, o, f32) + (accA + accB) + accC;
    stf(out, (size_t)n * 64 + o, acc, f32);
}

static inline size_t align64(size_t v) { return (v + 63) & ~(size_t)63; }

extern "C" void kernel_launch(void* const* d_in, const int* in_sizes, int n_in,
                              void* d_out, int out_size, void* d_ws, size_t ws_size,
                              hipStream_t stream) {
    const void* x         = d_in[0];
    const void* edge_attr = d_in[1];
    const void* h_prev    = d_in[2];
    const int*  ei        = (const int*)d_in[3];
    const void* w1     = d_in[4];
    const void* b1     = d_in[5];
    const void* w2     = d_in[6];
    const void* b2     = d_in[7];
    const void* root   = d_in[8];
    const void* bias   = d_in[9];
    const void* tw1    = d_in[10];
    const void* tb1    = d_in[11];
    const void* tw2    = d_in[12];
    const void* tb2    = d_in[13];
    const void* tw3    = d_in[14];
    const void* tb3    = d_in[15];
    const void* proj_w = d_in[16];
    const void* proj_b = d_in[17];

    char* ws = (char*)d_ws;
    size_t off = 0;
    uint16_t* T      = (uint16_t*)(ws + off); off = align64(off + (size_t)NN * 2048 * 2);
    uint16_t* h_edge = (uint16_t*)(ws + off); off = align64(off + (size_t)NE * 32 * 2);
    float* xs_f   = (float*)(ws + off); off = align64(off + (size_t)NN * 32 * 4);
    float* root_f = (float*)(ws + off); off = align64(off + (size_t)2048 * 4);
    float* xb     = (float*)(ws + off); off = align64(off + (size_t)NN * 64 * 4);
    size_t zero_base = off;  // agg|indeg|outdeg|A|B|C|dv = 2,689,408 B (168088 float4)
    float* agg    = (float*)(ws + off); off = align64(off + (size_t)NN * 64 * 4);
    int* indeg    = (int*)(ws + off);   off = align64(off + (size_t)NN * 4);
    int* outdeg   = (int*)(ws + off);   off = align64(off + (size_t)NN * 4);
    float* Amat   = (float*)(ws + off); off = align64(off + (size_t)4096 * 4);
    float* Bmat   = (float*)(ws + off); off = align64(off + (size_t)4096 * 4);
    float* Cmat   = (float*)(ws + off); off = align64(off + (size_t)4096 * 4);
    float* dvec   = (float*)(ws + off); off = align64(off + (size_t)64 * 4);
    int* offs        = (int*)(ws + off); off = align64(off + (size_t)(NN + 64) * 4);
    int* rank        = (int*)(ws + off); off = align64(off + (size_t)NE * 4);
    int* sorted_src  = (int*)(ws + off); off = align64(off + (size_t)NE * 4);
    int* sorted_dst  = (int*)(ws + off); off = align64(off + (size_t)NE * 4);
    int* sorted_eid  = (int*)(ws + off); off = align64(off + (size_t)NE * 4);
    int* flag        = (int*)(ws + off); off = align64(off + 64);
    uint16_t* h_srt  = (uint16_t*)(ws + off);
    size_t off_end = off + (size_t)NE * 32 * 2;
    int hs_mode = (off_end <= ws_size) ? 1 : 0;  // host-side, deterministic

    k_init<<<658, 256, 0, stream>>>(x, (float4*)((char*)d_ws + zero_base), flag);
    k_prep<<<5436, 256, 0, stream>>>(x, root, tw1, tw2, tw3, tb1, tb2, tb3,
                                     proj_w, edge_attr, w1, b1, w2, b2, ei, flag,
                                     xs_f, root_f, Amat, Bmat, Cmat, dvec,
                                     outdeg, indeg, rank, h_edge, T, xb);
    k_scan<<<1, 1024, 0, stream>>>(outdeg, offs);
    k_scat<<<(NE + 255) / 256, 256, 0, stream>>>(ei, offs, rank,
                                                 sorted_src, sorted_dst, sorted_eid,
                                                 h_edge, h_srt, hs_mode);
    k_msg_g<<<(NE / CHUNK + 3) / 4, 256, 0, stream>>>(h_edge, h_srt, hs_mode, T, xb,
                                                      sorted_src, sorted_dst,
                                                      sorted_eid, agg);
    k_node_out<<<NN / 4, 256, 0, stream>>>(agg, indeg, xs_f, root_f, bias, h_prev,
                                           Amat, Bmat, Cmat, dvec, proj_b, flag, d_out);
}